// Round 1
// baseline (21448.270 us; speedup 1.0000x reference)
//
#include <hip/hip_runtime.h>
#include <hip/hip_bf16.h>

// ---------------- constants ----------------
#define BB   64     // batch
#define TT   200    // decoder steps
#define TE   512    // encoder positions
#define DD   256    // encoder dim / hidden
#define HH   256    // hidden
#define GG   768    // 3*H gates
#define INW  400    // mel in/out width
#define PN1  256
#define PN2  128

__device__ __forceinline__ float bf2f(unsigned short u) {
    return __uint_as_float(((unsigned)u) << 16);
}
__device__ __forceinline__ float fast_tanh(float x) {
    x = fminf(fmaxf(x, -15.f), 15.f);
    float e = __expf(2.f * x);
    return __fdividef(e - 1.f, e + 1.f);
}
__device__ __forceinline__ float sigm(float x) {
    return __fdividef(1.f, 1.f + __expf(-x));
}

#define FMA4(acc, w4, x0, x1, x2, x3) \
    acc = fmaf(x0, w4.x, acc); acc = fmaf(x1, w4.y, acc); \
    acc = fmaf(x2, w4.z, acc); acc = fmaf(x3, w4.w, acc)

// ---------------- generic tiled fp32 GEMM ----------------
// C[M,N] = A[M,K] @ B[K,N] (+bias) (+relu)
// AMODE: 0 normal, 1 shifted-mel (row r -> b=r/TT,t=r%TT; t==0 -> 0 else mel[b][t-1][k])
// SMODE: 0 fp32 row-major; 1 xgi remap [(r%TT)*GG + c]*64 + r/TT; 2 bf16 row-major; 3 fp32 transposed out[c*M+r]
template<int AMODE, int SMODE, bool RELU, bool BIAS>
__global__ __launch_bounds__(256) void gemm_k(
    const float* __restrict__ A, const float* __restrict__ Bm,
    const float* __restrict__ bias, void* __restrict__ Cp,
    int M, int N, int K, int lda, int ldb)
{
    __shared__ __align__(16) float As[16][68];
    __shared__ __align__(16) float Bs[16][68];
    int tid = threadIdx.x;
    int m0 = blockIdx.y * 64, n0 = blockIdx.x * 64;
    int tx = tid & 15, ty = tid >> 4;
    float acc[4][4] = {};
    for (int k0 = 0; k0 < K; k0 += 16) {
        {   // A tile: thread -> row=tid>>2 (0..63), kq=tid&3
            int row = tid >> 2, kq = tid & 3;
            int gr = m0 + row;
            float4 a4;
            if (AMODE == 0) {
                a4 = *(const float4*)(A + (size_t)gr * lda + k0 + kq * 4);
            } else {
                int bb = gr / TT, t = gr % TT;
                if (t == 0) a4 = make_float4(0.f, 0.f, 0.f, 0.f);
                else a4 = *(const float4*)(A + ((size_t)bb * TT + (t - 1)) * INW + k0 + kq * 4);
            }
            As[kq * 4 + 0][row] = a4.x; As[kq * 4 + 1][row] = a4.y;
            As[kq * 4 + 2][row] = a4.z; As[kq * 4 + 3][row] = a4.w;
            // B tile: thread -> kk=tid>>4, nq=tid&15
            int kk = tid >> 4, nq = tid & 15;
            int gc = n0 + nq * 4;
            float4 b4;
            if (gc + 3 < N) {
                b4 = *(const float4*)(Bm + (size_t)(k0 + kk) * ldb + gc);
            } else {
                b4.x = (gc + 0 < N) ? Bm[(size_t)(k0 + kk) * ldb + gc + 0] : 0.f;
                b4.y = (gc + 1 < N) ? Bm[(size_t)(k0 + kk) * ldb + gc + 1] : 0.f;
                b4.z = (gc + 2 < N) ? Bm[(size_t)(k0 + kk) * ldb + gc + 2] : 0.f;
                b4.w = (gc + 3 < N) ? Bm[(size_t)(k0 + kk) * ldb + gc + 3] : 0.f;
            }
            *(float4*)&Bs[kk][nq * 4] = b4;
        }
        __syncthreads();
#pragma unroll
        for (int kk = 0; kk < 16; ++kk) {
            float4 av = *(const float4*)&As[kk][ty * 4];
            float4 bv = *(const float4*)&Bs[kk][tx * 4];
            acc[0][0] = fmaf(av.x, bv.x, acc[0][0]); acc[0][1] = fmaf(av.x, bv.y, acc[0][1]);
            acc[0][2] = fmaf(av.x, bv.z, acc[0][2]); acc[0][3] = fmaf(av.x, bv.w, acc[0][3]);
            acc[1][0] = fmaf(av.y, bv.x, acc[1][0]); acc[1][1] = fmaf(av.y, bv.y, acc[1][1]);
            acc[1][2] = fmaf(av.y, bv.z, acc[1][2]); acc[1][3] = fmaf(av.y, bv.w, acc[1][3]);
            acc[2][0] = fmaf(av.z, bv.x, acc[2][0]); acc[2][1] = fmaf(av.z, bv.y, acc[2][1]);
            acc[2][2] = fmaf(av.z, bv.z, acc[2][2]); acc[2][3] = fmaf(av.z, bv.w, acc[2][3]);
            acc[3][0] = fmaf(av.w, bv.x, acc[3][0]); acc[3][1] = fmaf(av.w, bv.y, acc[3][1]);
            acc[3][2] = fmaf(av.w, bv.z, acc[3][2]); acc[3][3] = fmaf(av.w, bv.w, acc[3][3]);
        }
        __syncthreads();
    }
#pragma unroll
    for (int i = 0; i < 4; ++i) {
#pragma unroll
        for (int j = 0; j < 4; ++j) {
            int r = m0 + ty * 4 + i, c = n0 + tx * 4 + j;
            if (c >= N) continue;
            float v = acc[i][j];
            if (BIAS) v += bias[c];
            if (RELU) v = fmaxf(v, 0.f);
            if (SMODE == 0) ((float*)Cp)[(size_t)r * N + c] = v;
            else if (SMODE == 1) ((float*)Cp)[((size_t)(r % TT) * GG + c) * 64 + (r / TT)] = v;
            else if (SMODE == 2) ((__hip_bfloat16*)Cp)[(size_t)r * N + c] = __float2bfloat16(v);
            else ((float*)Cp)[(size_t)c * M + r] = v;
        }
    }
}

// ---------------- transpose: out[c*IR + r] = in[(r+rowoff)*IC + c] ----------------
template<bool BF16>
__global__ __launch_bounds__(256) void trans_k(const float* __restrict__ in, int IR, int IC,
                                               int rowoff, void* __restrict__ out)
{
    int idx = blockIdx.x * 256 + threadIdx.x;
    if (idx >= IR * IC) return;
    int c = idx / IR, r = idx % IR;
    float v = in[(size_t)(r + rowoff) * IC + c];
    if (BF16) ((__hip_bfloat16*)out)[idx] = __float2bfloat16(v);
    else ((float*)out)[idx] = v;
}

__global__ __launch_bounds__(256) void tobf16_k(const float* __restrict__ in,
                                                __hip_bfloat16* __restrict__ out, size_t n)
{
    for (size_t i = (size_t)blockIdx.x * 256 + threadIdx.x; i < n; i += (size_t)gridDim.x * 256)
        out[i] = __float2bfloat16(in[i]);
}

// out[c] = bih[c] + sum_j projb[j] * W[j*N + c]
__global__ __launch_bounds__(256) void bfuse_k(const float* __restrict__ bih,
                                               const float* __restrict__ projb,
                                               const float* __restrict__ W, int N,
                                               float* __restrict__ out)
{
    int c = blockIdx.x * 256 + threadIdx.x;
    if (c >= N) return;
    float s = bih[c];
    for (int j = 0; j < 256; ++j) s = fmaf(projb[j], W[(size_t)j * N + c], s);
    out[c] = s;
}

// ---------------- step kernels ----------------
// S1: attention GRU. grid 128 x 256 (2 units/block).
__global__ __launch_bounds__(256) void s1_attgru(
    const float* __restrict__ xgi_t, const float* __restrict__ ctxT,
    const float* __restrict__ hT, float* __restrict__ hTn,
    const float* __restrict__ WihcT, const float* __restrict__ WhhT,
    const float* __restrict__ bhh)
{
    int tid = threadIdx.x;
    int b = tid & 63, q = tid >> 6;
    int ul = q >> 1, role = q & 1;
    int u = blockIdx.x * 2 + ul;
    const float* st = (role == 0) ? ctxT : hT;
    const float* W  = (role == 0) ? WihcT : WhhT;
    const float* w0 = W + (size_t)u * 256;
    const float* w1 = W + (size_t)(256 + u) * 256;
    const float* w2 = W + (size_t)(512 + u) * 256;
    float s0 = 0.f, s1 = 0.f, s2 = 0.f;
    for (int j = 0; j < 256; j += 4) {
        float4 a0 = *(const float4*)(w0 + j);
        float4 a1 = *(const float4*)(w1 + j);
        float4 a2 = *(const float4*)(w2 + j);
        float x0 = st[(j + 0) * 64 + b], x1 = st[(j + 1) * 64 + b];
        float x2 = st[(j + 2) * 64 + b], x3 = st[(j + 3) * 64 + b];
        FMA4(s0, a0, x0, x1, x2, x3);
        FMA4(s1, a1, x0, x1, x2, x3);
        FMA4(s2, a2, x0, x1, x2, x3);
    }
    __shared__ float xch[2][3][64];
    if (role == 1) {
        xch[ul][0][b] = s0 + bhh[u];
        xch[ul][1][b] = s1 + bhh[256 + u];
        xch[ul][2][b] = s2 + bhh[512 + u];
    }
    __syncthreads();
    if (role == 0) {
        float ir = s0 + xgi_t[(size_t)u * 64 + b];
        float iz = s1 + xgi_t[(size_t)(256 + u) * 64 + b];
        float in_ = s2 + xgi_t[(size_t)(512 + u) * 64 + b];
        float hr = xch[ul][0][b], hz = xch[ul][1][b], hn = xch[ul][2][b];
        float r = sigm(ir + hr), z = sigm(iz + hz);
        float n = fast_tanh(in_ + r * hn);
        float hp = hT[(size_t)u * 64 + b];
        hTn[(size_t)u * 64 + b] = (1.f - z) * n + z * hp;
    }
}

// S2a: q + scores. grid 256 (= batch*4 quarters) x 256.
__global__ __launch_bounds__(256) void s2a_scores(
    const float* __restrict__ hTn, const __hip_bfloat16* __restrict__ WqT,
    const __hip_bfloat16* __restrict__ pmB, const float* __restrict__ v,
    float* __restrict__ evals)
{
    int b = blockIdx.x >> 2, quarter = blockIdx.x & 3;
    int tid = threadIdx.x;
    __shared__ float hsh[256], qsh[256], vsh[256];
    hsh[tid] = hTn[(size_t)tid * 64 + b];
    vsh[tid] = v[tid];
    __syncthreads();
    {
        const unsigned short* wr = (const unsigned short*)(WqT + (size_t)tid * 256);
        float acc = 0.f;
        for (int j = 0; j < 256; j += 4) {
            ushort4 w4 = *(const ushort4*)(wr + j);
            acc = fmaf(hsh[j + 0], bf2f(w4.x), acc);
            acc = fmaf(hsh[j + 1], bf2f(w4.y), acc);
            acc = fmaf(hsh[j + 2], bf2f(w4.z), acc);
            acc = fmaf(hsh[j + 3], bf2f(w4.w), acc);
        }
        qsh[tid] = acc;
    }
    __syncthreads();
    int jl = tid >> 1, half = tid & 1;
    int j = quarter * 128 + jl;
    const unsigned short* pr =
        (const unsigned short*)(pmB + ((size_t)b * TE + j) * 256 + half * 128);
    int kb = half * 128;
    float acc = 0.f;
    for (int k = 0; k < 128; k += 4) {
        ushort4 m4 = *(const ushort4*)(pr + k);
        acc = fmaf(vsh[kb + k + 0], fast_tanh(bf2f(m4.x) + qsh[kb + k + 0]), acc);
        acc = fmaf(vsh[kb + k + 1], fast_tanh(bf2f(m4.y) + qsh[kb + k + 1]), acc);
        acc = fmaf(vsh[kb + k + 2], fast_tanh(bf2f(m4.z) + qsh[kb + k + 2]), acc);
        acc = fmaf(vsh[kb + k + 3], fast_tanh(bf2f(m4.w) + qsh[kb + k + 3]), acc);
    }
    acc += __shfl_xor(acc, 1);
    if (half == 0) evals[(size_t)b * TE + j] = acc;
}

// S2b: softmax + aligns + ctx. grid 64 x 256.
__global__ __launch_bounds__(256) void s2b_ctx(
    const float* __restrict__ evals, const __hip_bfloat16* __restrict__ encB,
    float* __restrict__ ctxTn, float* __restrict__ aligns, int t)
{
    int b = blockIdx.x, tid = threadIdx.x;
    float e0 = evals[(size_t)b * TE + tid];
    float e1 = evals[(size_t)b * TE + 256 + tid];
    float m = fmaxf(e0, e1);
    for (int o = 32; o; o >>= 1) m = fmaxf(m, __shfl_xor(m, o));
    __shared__ float red[4], red2[4], ash[512];
    if ((tid & 63) == 0) red[tid >> 6] = m;
    __syncthreads();
    m = fmaxf(fmaxf(red[0], red[1]), fmaxf(red[2], red[3]));
    float p0 = __expf(e0 - m), p1 = __expf(e1 - m);
    float s = p0 + p1;
    for (int o = 32; o; o >>= 1) s += __shfl_xor(s, o);
    if ((tid & 63) == 0) red2[tid >> 6] = s;
    __syncthreads();
    s = red2[0] + red2[1] + red2[2] + red2[3];
    float inv = __fdividef(1.f, s);
    float a0 = p0 * inv, a1 = p1 * inv;
    ash[tid] = a0; ash[256 + tid] = a1;
    size_t ao = ((size_t)b * TT + t) * TE;
    aligns[ao + tid] = a0;
    aligns[ao + 256 + tid] = a1;
    __syncthreads();
    const unsigned short* er = (const unsigned short*)(encB + (size_t)b * TE * 256) + tid;
    float acc = 0.f;
    for (int j = 0; j < 512; j += 2) {
        acc = fmaf(ash[j + 0], bf2f(er[(size_t)(j + 0) * 256]), acc);
        acc = fmaf(ash[j + 1], bf2f(er[(size_t)(j + 1) * 256]), acc);
    }
    ctxTn[(size_t)tid * 64 + b] = acc;
}

// S4: dec1 GRU (proj folded into F1). grid 128 x 256.
__global__ __launch_bounds__(256) void s4_dec1(
    const float* __restrict__ hTn, const float* __restrict__ ctxTn,
    const float* __restrict__ h1T, float* __restrict__ h1Tn,
    const float* __restrict__ F1T, const float* __restrict__ Whh1T,
    const float* __restrict__ bf1, const float* __restrict__ bhh1)
{
    int tid = threadIdx.x;
    int b = tid & 63, q = tid >> 6;
    int ul = q >> 1, role = q & 1;
    int u = blockIdx.x * 2 + ul;
    float s0 = 0.f, s1 = 0.f, s2 = 0.f;
    __shared__ float xch[2][3][64];
    if (role == 0) {
        const float* w0 = F1T + (size_t)u * 512;
        const float* w1 = F1T + (size_t)(256 + u) * 512;
        const float* w2 = F1T + (size_t)(512 + u) * 512;
        for (int j = 0; j < 256; j += 4) {
            float4 a0 = *(const float4*)(w0 + j);
            float4 a1 = *(const float4*)(w1 + j);
            float4 a2 = *(const float4*)(w2 + j);
            float x0 = hTn[(j + 0) * 64 + b], x1 = hTn[(j + 1) * 64 + b];
            float x2 = hTn[(j + 2) * 64 + b], x3 = hTn[(j + 3) * 64 + b];
            FMA4(s0, a0, x0, x1, x2, x3);
            FMA4(s1, a1, x0, x1, x2, x3);
            FMA4(s2, a2, x0, x1, x2, x3);
        }
        for (int j = 0; j < 256; j += 4) {
            float4 a0 = *(const float4*)(w0 + 256 + j);
            float4 a1 = *(const float4*)(w1 + 256 + j);
            float4 a2 = *(const float4*)(w2 + 256 + j);
            float x0 = ctxTn[(j + 0) * 64 + b], x1 = ctxTn[(j + 1) * 64 + b];
            float x2 = ctxTn[(j + 2) * 64 + b], x3 = ctxTn[(j + 3) * 64 + b];
            FMA4(s0, a0, x0, x1, x2, x3);
            FMA4(s1, a1, x0, x1, x2, x3);
            FMA4(s2, a2, x0, x1, x2, x3);
        }
        s0 += bf1[u]; s1 += bf1[256 + u]; s2 += bf1[512 + u];
    } else {
        const float* w0 = Whh1T + (size_t)u * 256;
        const float* w1 = Whh1T + (size_t)(256 + u) * 256;
        const float* w2 = Whh1T + (size_t)(512 + u) * 256;
        for (int j = 0; j < 256; j += 4) {
            float4 a0 = *(const float4*)(w0 + j);
            float4 a1 = *(const float4*)(w1 + j);
            float4 a2 = *(const float4*)(w2 + j);
            float x0 = h1T[(j + 0) * 64 + b], x1 = h1T[(j + 1) * 64 + b];
            float x2 = h1T[(j + 2) * 64 + b], x3 = h1T[(j + 3) * 64 + b];
            FMA4(s0, a0, x0, x1, x2, x3);
            FMA4(s1, a1, x0, x1, x2, x3);
            FMA4(s2, a2, x0, x1, x2, x3);
        }
        xch[ul][0][b] = s0 + bhh1[u];
        xch[ul][1][b] = s1 + bhh1[256 + u];
        xch[ul][2][b] = s2 + bhh1[512 + u];
    }
    __syncthreads();
    if (role == 0) {
        float hr = xch[ul][0][b], hz = xch[ul][1][b], hn = xch[ul][2][b];
        float r = sigm(s0 + hr), z = sigm(s1 + hz);
        float n = fast_tanh(s2 + r * hn);
        float hp = h1T[(size_t)u * 64 + b];
        h1Tn[(size_t)u * 64 + b] = (1.f - z) * n + z * hp;
    }
}

// S5: dec2 GRU. grid 128 x 256.
__global__ __launch_bounds__(256) void s5_dec2(
    const float* __restrict__ hTn, const float* __restrict__ ctxTn,
    const float* __restrict__ h1Tn, const float* __restrict__ h2T,
    float* __restrict__ h2Tn,
    const float* __restrict__ F2T, const float* __restrict__ Wih2T,
    const float* __restrict__ Whh2T,
    const float* __restrict__ b2c, const float* __restrict__ bhh2)
{
    int tid = threadIdx.x;
    int b = tid & 63, q = tid >> 6;
    int ul = q >> 1, role = q & 1;
    int u = blockIdx.x * 2 + ul;
    __shared__ float xch[2][6][64];
    float s0 = 0.f, s1 = 0.f, s2 = 0.f;
    if (role == 0) {
        const float* w0 = F2T + (size_t)u * 512;
        const float* w1 = F2T + (size_t)(256 + u) * 512;
        const float* w2 = F2T + (size_t)(512 + u) * 512;
        for (int j = 0; j < 256; j += 4) {
            float4 a0 = *(const float4*)(w0 + j);
            float4 a1 = *(const float4*)(w1 + j);
            float4 a2 = *(const float4*)(w2 + j);
            float x0 = hTn[(j + 0) * 64 + b], x1 = hTn[(j + 1) * 64 + b];
            float x2 = hTn[(j + 2) * 64 + b], x3 = hTn[(j + 3) * 64 + b];
            FMA4(s0, a0, x0, x1, x2, x3);
            FMA4(s1, a1, x0, x1, x2, x3);
            FMA4(s2, a2, x0, x1, x2, x3);
        }
        for (int j = 0; j < 256; j += 4) {
            float4 a0 = *(const float4*)(w0 + 256 + j);
            float4 a1 = *(const float4*)(w1 + 256 + j);
            float4 a2 = *(const float4*)(w2 + 256 + j);
            float x0 = ctxTn[(j + 0) * 64 + b], x1 = ctxTn[(j + 1) * 64 + b];
            float x2 = ctxTn[(j + 2) * 64 + b], x3 = ctxTn[(j + 3) * 64 + b];
            FMA4(s0, a0, x0, x1, x2, x3);
            FMA4(s1, a1, x0, x1, x2, x3);
            FMA4(s2, a2, x0, x1, x2, x3);
        }
        s0 += b2c[u]; s1 += b2c[256 + u]; s2 += b2c[512 + u];
    } else {
        const float* g0 = Whh2T + (size_t)u * 256;
        const float* g1 = Whh2T + (size_t)(256 + u) * 256;
        const float* g2 = Whh2T + (size_t)(512 + u) * 256;
        const float* x0p = Wih2T + (size_t)u * 256;
        const float* x1p = Wih2T + (size_t)(256 + u) * 256;
        const float* x2p = Wih2T + (size_t)(512 + u) * 256;
        float t0 = 0.f, t1 = 0.f, t2 = 0.f;
        for (int j = 0; j < 256; j += 4) {
            float4 a0 = *(const float4*)(g0 + j);
            float4 a1 = *(const float4*)(g1 + j);
            float4 a2 = *(const float4*)(g2 + j);
            float x0 = h2T[(j + 0) * 64 + b], x1 = h2T[(j + 1) * 64 + b];
            float x2 = h2T[(j + 2) * 64 + b], x3 = h2T[(j + 3) * 64 + b];
            FMA4(s0, a0, x0, x1, x2, x3);
            FMA4(s1, a1, x0, x1, x2, x3);
            FMA4(s2, a2, x0, x1, x2, x3);
        }
        for (int j = 0; j < 256; j += 4) {
            float4 a0 = *(const float4*)(x0p + j);
            float4 a1 = *(const float4*)(x1p + j);
            float4 a2 = *(const float4*)(x2p + j);
            float x0 = h1Tn[(j + 0) * 64 + b], x1 = h1Tn[(j + 1) * 64 + b];
            float x2 = h1Tn[(j + 2) * 64 + b], x3 = h1Tn[(j + 3) * 64 + b];
            FMA4(t0, a0, x0, x1, x2, x3);
            FMA4(t1, a1, x0, x1, x2, x3);
            FMA4(t2, a2, x0, x1, x2, x3);
        }
        xch[ul][0][b] = s0 + bhh2[u];
        xch[ul][1][b] = s1 + bhh2[256 + u];
        xch[ul][2][b] = s2 + bhh2[512 + u];
        xch[ul][3][b] = t0; xch[ul][4][b] = t1; xch[ul][5][b] = t2;
    }
    __syncthreads();
    if (role == 0) {
        float hr = xch[ul][0][b], hz = xch[ul][1][b], hn = xch[ul][2][b];
        float ir = s0 + xch[ul][3][b], iz = s1 + xch[ul][4][b], in_ = s2 + xch[ul][5][b];
        float r = sigm(ir + hr), z = sigm(iz + hz);
        float n = fast_tanh(in_ + r * hn);
        float hp = h2T[(size_t)u * 64 + b];
        h2Tn[(size_t)u * 64 + b] = (1.f - z) * n + z * hp;
    }
}

// S6: mel out. grid 100 x 256. out = (h1'+h2')@mel + [h,c]@FM + const
__global__ __launch_bounds__(256) void s6_mel(
    const float* __restrict__ h1Tn, const float* __restrict__ h2Tn,
    const float* __restrict__ hTn, const float* __restrict__ ctxTn,
    const float* __restrict__ melT, const float* __restrict__ FMT,
    const float* __restrict__ bmc, float* __restrict__ outs, int t)
{
    int tid = threadIdx.x;
    int b = tid & 63, q = tid >> 6;
    int c = blockIdx.x * 4 + q;
    const float* w = melT + (size_t)c * 256;
    const float* f = FMT + (size_t)c * 512;
    float acc = bmc[c];
    for (int j = 0; j < 256; j += 4) {
        float4 w4 = *(const float4*)(w + j);
        float x0 = h1Tn[(j + 0) * 64 + b] + h2Tn[(j + 0) * 64 + b];
        float x1 = h1Tn[(j + 1) * 64 + b] + h2Tn[(j + 1) * 64 + b];
        float x2 = h1Tn[(j + 2) * 64 + b] + h2Tn[(j + 2) * 64 + b];
        float x3 = h1Tn[(j + 3) * 64 + b] + h2Tn[(j + 3) * 64 + b];
        FMA4(acc, w4, x0, x1, x2, x3);
    }
    for (int j = 0; j < 256; j += 4) {
        float4 f4 = *(const float4*)(f + j);
        float x0 = hTn[(j + 0) * 64 + b], x1 = hTn[(j + 1) * 64 + b];
        float x2 = hTn[(j + 2) * 64 + b], x3 = hTn[(j + 3) * 64 + b];
        FMA4(acc, f4, x0, x1, x2, x3);
    }
    for (int j = 0; j < 256; j += 4) {
        float4 f4 = *(const float4*)(f + 256 + j);
        float x0 = ctxTn[(j + 0) * 64 + b], x1 = ctxTn[(j + 1) * 64 + b];
        float x2 = ctxTn[(j + 2) * 64 + b], x3 = ctxTn[(j + 3) * 64 + b];
        FMA4(acc, f4, x0, x1, x2, x3);
    }
    outs[((size_t)b * TT + t) * INW + c] = acc;
}

// ---------------- host launcher ----------------
extern "C" void kernel_launch(void* const* d_in, const int* in_sizes, int n_in,
                              void* d_out, int out_size, void* d_ws, size_t ws_size,
                              hipStream_t stream) {
    const float* enc     = (const float*)d_in[0];
    const float* mel     = (const float*)d_in[1];
    const float* pw1     = (const float*)d_in[2];
    const float* pb1     = (const float*)d_in[3];
    const float* pw2     = (const float*)d_in[4];
    const float* pb2     = (const float*)d_in[5];
    const float* att_wih = (const float*)d_in[6];
    const float* att_whh = (const float*)d_in[7];
    const float* att_bih = (const float*)d_in[8];
    const float* att_bhh = (const float*)d_in[9];
    const float* mem_w   = (const float*)d_in[10];
    const float* query_w = (const float*)d_in[11];
    const float* att_v   = (const float*)d_in[12];
    const float* proj_w  = (const float*)d_in[13];
    const float* proj_b  = (const float*)d_in[14];
    const float* d1_wih  = (const float*)d_in[15];
    const float* d1_whh  = (const float*)d_in[16];
    const float* d1_bih  = (const float*)d_in[17];
    const float* d1_bhh  = (const float*)d_in[18];
    const float* d2_wih  = (const float*)d_in[19];
    const float* d2_whh  = (const float*)d_in[20];
    const float* d2_bih  = (const float*)d_in[21];
    const float* d2_bhh  = (const float*)d_in[22];
    const float* mel_w   = (const float*)d_in[23];
    const float* mel_b   = (const float*)d_in[24];

    float* outs = (float*)d_out;
    float* aligns = outs + (size_t)BB * TT * INW;

    char* p = (char*)d_ws;
    auto take = [&](size_t bytes) -> char* {
        char* r = p;
        p += (bytes + 255) & ~(size_t)255;
        return r;
    };
    const size_t SB = (size_t)HH * BB;         // one state buffer, floats
    float* states = (float*)take(8 * SB * 4);  // attH[2], ctx[2], h1[2], h2[2]
    float* attH = states;
    float* ctxS = states + 2 * SB;
    float* h1S  = states + 4 * SB;
    float* h2S  = states + 6 * SB;
    float* xgi = (float*)take((size_t)TT * GG * BB * 4);
    float* X1  = (float*)take((size_t)BB * TT * PN1 * 4);
    float* X2  = (float*)take((size_t)BB * TT * PN2 * 4);
    __hip_bfloat16* pmB  = (__hip_bfloat16*)take((size_t)BB * TE * DD * 2);
    __hip_bfloat16* encB = (__hip_bfloat16*)take((size_t)BB * TE * DD * 2);
    float* WihcT = (float*)take((size_t)GG * 256 * 4);
    float* WhhT  = (float*)take((size_t)GG * 256 * 4);
    float* Whh1T = (float*)take((size_t)GG * 256 * 4);
    float* Whh2T = (float*)take((size_t)GG * 256 * 4);
    float* Wih2T = (float*)take((size_t)GG * 256 * 4);
    float* melT  = (float*)take((size_t)INW * 256 * 4);
    float* F1T   = (float*)take((size_t)GG * 512 * 4);
    float* F2T   = (float*)take((size_t)GG * 512 * 4);
    float* FMT   = (float*)take((size_t)INW * 512 * 4);
    __hip_bfloat16* WqT = (__hip_bfloat16*)take((size_t)256 * 256 * 2);
    float* bf1 = (float*)take(GG * 4);
    float* b2c = (float*)take(GG * 4);
    float* bmc = (float*)take(INW * 4);
    float* evals = (float*)take((size_t)BB * TE * 4);

    hipMemsetAsync(states, 0, 8 * SB * 4, stream);

    // weight transposes
    trans_k<false><<<(256 * GG + 255) / 256, 256, 0, stream>>>(att_wih, 256, GG, 128, WihcT);
    trans_k<false><<<(256 * GG + 255) / 256, 256, 0, stream>>>(att_whh, 256, GG, 0, WhhT);
    trans_k<false><<<(256 * GG + 255) / 256, 256, 0, stream>>>(d1_whh, 256, GG, 0, Whh1T);
    trans_k<false><<<(256 * GG + 255) / 256, 256, 0, stream>>>(d2_whh, 256, GG, 0, Whh2T);
    trans_k<false><<<(256 * GG + 255) / 256, 256, 0, stream>>>(d2_wih, 256, GG, 0, Wih2T);
    trans_k<false><<<(256 * INW + 255) / 256, 256, 0, stream>>>(mel_w, 256, INW, 0, melT);
    trans_k<true><<<(256 * 256 + 255) / 256, 256, 0, stream>>>(query_w, 256, 256, 0, WqT);
    tobf16_k<<<8192, 256, 0, stream>>>(enc, encB, (size_t)BB * TE * DD);
    bfuse_k<<<3, 256, 0, stream>>>(d1_bih, proj_b, d1_wih, GG, bf1);
    bfuse_k<<<3, 256, 0, stream>>>(d2_bih, proj_b, d2_wih, GG, b2c);
    bfuse_k<<<2, 256, 0, stream>>>(mel_b, proj_b, mel_w, INW, bmc);

    // precompute GEMMs
    gemm_k<1, 0, true, true><<<dim3(PN1 / 64, BB * TT / 64), 256, 0, stream>>>(
        mel, pw1, pb1, X1, BB * TT, PN1, INW, INW, PN1);
    gemm_k<0, 0, true, true><<<dim3(PN2 / 64, BB * TT / 64), 256, 0, stream>>>(
        X1, pw2, pb2, X2, BB * TT, PN2, PN1, PN1, PN2);
    gemm_k<0, 1, false, true><<<dim3(GG / 64, BB * TT / 64), 256, 0, stream>>>(
        X2, att_wih, att_bih, xgi, BB * TT, GG, PN2, PN2, GG);
    gemm_k<0, 2, false, false><<<dim3(DD / 64, BB * TE / 64), 256, 0, stream>>>(
        enc, mem_w, nullptr, pmB, BB * TE, DD, DD, DD, DD);
    gemm_k<0, 3, false, false><<<dim3(GG / 64, 512 / 64), 256, 0, stream>>>(
        proj_w, d1_wih, nullptr, F1T, 512, GG, 256, 256, GG);
    gemm_k<0, 3, false, false><<<dim3(GG / 64, 512 / 64), 256, 0, stream>>>(
        proj_w, d2_wih, nullptr, F2T, 512, GG, 256, 256, GG);
    gemm_k<0, 3, false, false><<<dim3((INW + 63) / 64, 512 / 64), 256, 0, stream>>>(
        proj_w, mel_w, nullptr, FMT, 512, INW, 256, 256, INW);

    // recurrent loop
    for (int t = 0; t < TT; ++t) {
        int cur = t & 1, nxt = cur ^ 1;
        float* hC = attH + cur * SB;  float* hN = attH + nxt * SB;
        float* cC = ctxS + cur * SB;  float* cN = ctxS + nxt * SB;
        float* h1C = h1S + cur * SB;  float* h1N = h1S + nxt * SB;
        float* h2C = h2S + cur * SB;  float* h2N = h2S + nxt * SB;

        s1_attgru<<<128, 256, 0, stream>>>(xgi + (size_t)t * GG * BB, cC, hC, hN,
                                           WihcT, WhhT, att_bhh);
        s2a_scores<<<256, 256, 0, stream>>>(hN, WqT, pmB, att_v, evals);
        s2b_ctx<<<64, 256, 0, stream>>>(evals, encB, cN, aligns, t);
        s4_dec1<<<128, 256, 0, stream>>>(hN, cN, h1C, h1N, F1T, Whh1T, bf1, d1_bhh);
        s5_dec2<<<128, 256, 0, stream>>>(hN, cN, h1N, h2C, h2N, F2T, Wih2T, Whh2T,
                                         b2c, d2_bhh);
        s6_mel<<<100, 256, 0, stream>>>(h1N, h2N, hN, cN, melT, FMT, bmc, outs, t);
    }
}